// Round 4
// baseline (201.437 us; speedup 1.0000x reference)
//
#include <hip/hip_runtime.h>
#include <hip/hip_bf16.h>
#include <cstdint>

typedef __attribute__((ext_vector_type(8))) __bf16 bf16x8;
typedef __attribute__((ext_vector_type(4))) float f32x4;

static __device__ __forceinline__ unsigned short f2bf(float f) {
  return __builtin_bit_cast(unsigned short, (__bf16)f);
}
static __device__ __forceinline__ unsigned pack2(float a, float b) {
  return (unsigned)f2bf(a) | ((unsigned)f2bf(b) << 16);
}

// ---------------- small prep kernels ----------------

__global__ void transpose_w_kernel(const float* __restrict__ W1, const float* __restrict__ W2,
                                   unsigned short* __restrict__ W1t, unsigned short* __restrict__ W2t) {
  int i = blockIdx.x * 256 + threadIdx.x;
  int k = i >> 8, n = i & 255;
  W1t[n * 256 + k] = f2bf(W1[k * 256 + n]);
  W2t[n * 256 + k] = f2bf(W2[k * 256 + n]);
}

// x2 = linear2x(sum of 4 bf16 K-split slices of h); vectorized ushort4.
// grid 2048 x 256: wave = one output row, thread = 4 cols.
__global__ void upsample_kernel(const unsigned short* __restrict__ hs,  // [4][4096][256]
                                unsigned short* __restrict__ x2b, float* __restrict__ sq) {
  int row = blockIdx.x * 4 + (threadIdx.x >> 6);
  int c = (threadIdx.x & 63) * 4;
  float s = (row + 0.5f) * 0.5f - 0.5f;
  s = fminf(fmaxf(s, 0.0f), 4095.0f);
  float fl = floorf(s);
  int i0 = (int)fl;
  int i1 = min((int)fl + 1, 4095);
  float w = s - fl;
  float v0[4] = {0.f, 0.f, 0.f, 0.f}, v1[4] = {0.f, 0.f, 0.f, 0.f};
  #pragma unroll
  for (int k = 0; k < 4; ++k) {
    ushort4 u0 = *(const ushort4*)&hs[(size_t)k * 4096 * 256 + i0 * 256 + c];
    ushort4 u1 = *(const ushort4*)&hs[(size_t)k * 4096 * 256 + i1 * 256 + c];
    v0[0] += __builtin_bit_cast(float, (unsigned)u0.x << 16);
    v0[1] += __builtin_bit_cast(float, (unsigned)u0.y << 16);
    v0[2] += __builtin_bit_cast(float, (unsigned)u0.z << 16);
    v0[3] += __builtin_bit_cast(float, (unsigned)u0.w << 16);
    v1[0] += __builtin_bit_cast(float, (unsigned)u1.x << 16);
    v1[1] += __builtin_bit_cast(float, (unsigned)u1.y << 16);
    v1[2] += __builtin_bit_cast(float, (unsigned)u1.z << 16);
    v1[3] += __builtin_bit_cast(float, (unsigned)u1.w << 16);
  }
  float p = 0.f;
  ushort4 st;
  unsigned short* sp = (unsigned short*)&st;
  #pragma unroll
  for (int e = 0; e < 4; ++e) {
    float v = v0[e] * (1.0f - w) + v1[e] * w;
    sp[e] = f2bf(v);
    p += v * v;
  }
  *(ushort4*)&x2b[(size_t)row * 256 + c] = st;
  #pragma unroll
  for (int m = 32; m > 0; m >>= 1) p += __shfl_down(p, m, 64);
  if ((threadIdx.x & 63) == 0) sq[row] = p;
}

// final per-row lex-min over the 64 partial slots
__global__ void argmin_reduce_kernel(const float* __restrict__ pv,
                                     const unsigned* __restrict__ pidx,
                                     unsigned* __restrict__ pck) {
  int row = blockIdx.x * 256 + threadIdx.x;
  float bv = 3.402823466e38f;
  unsigned bidx = 0;
  for (int c = 0; c < 64; ++c) {
    float v = pv[(size_t)c * 8192 + row];
    unsigned id = pidx[(size_t)c * 8192 + row];
    if (v < bv || (v == bv && id < bidx)) { bv = v; bidx = id; }
  }
  pck[row] = bidx;
}

__global__ void gather_kernel(const float* __restrict__ support,
                              const unsigned* __restrict__ pck,
                              float* __restrict__ out) {
  int gid = blockIdx.x * 256 + threadIdx.x;
  int row = gid >> 6;
  int c4 = (gid & 63) * 4;
  unsigned idx = pck[row];
  *(float4*)&out[(size_t)row * 256 + c4] = *(const float4*)&support[(size_t)idx * 256 + c4];
}

// ---------------- register-streaming GEMM-NT (no LDS, no barriers) ----------
// C = A * B^T. A: [M][K] (fp32 if AF32 else bf16), lda=K. B: [N][K] bf16, ldb=K.
// Block = 4 waves stacked in M: BM=128 (wave=32 rows, FM=2), BN=64 (FN=4).
// K per block = NT*64, kbase = blockIdx.z * NT*64.
// EPI 0: Cf[m][n] fp32, ld=Nld.  EPI 1: Ct[n][m] bf16 transposed, ld=Mt.
// EPI 3: Cb[m][n] bf16 + K-split slice offset blockIdx.z * sliceStride.
template <int NT, int EPI, bool AF32>
__launch_bounds__(256)
__global__ void gemm_reg_kernel(const void* __restrict__ Ap, int lda,
                                const unsigned short* __restrict__ Bp, int ldb,
                                int Nld, int Mt, size_t sliceStride,
                                float* __restrict__ Cf, unsigned short* __restrict__ Cb) {
  const int tid = threadIdx.x;
  const int wid = tid >> 6;
  const int lane = tid & 63;
  const int g = lane >> 4;
  const int lr = lane & 15;
  const int m0 = blockIdx.x * 128 + wid * 32;     // wave's first row
  const int n0 = blockIdx.y * 64;
  const int kb = blockIdx.z * (NT * 64);

  f32x4 acc[2][4];
  const f32x4 fzero = {0.f, 0.f, 0.f, 0.f};
  #pragma unroll
  for (int i = 0; i < 2; ++i)
    #pragma unroll
    for (int j = 0; j < 4; ++j) acc[i][j] = fzero;

  // per-lane base pointers (fragment layout: row = l&15, k-window = (l>>4)*8)
  const float* Af[2];
  const unsigned short* Ab[2];
  const unsigned short* Bb[4];
  #pragma unroll
  for (int i = 0; i < 2; ++i) {
    int row = m0 + i * 16 + lr;
    if constexpr (AF32) Af[i] = (const float*)Ap + (size_t)row * lda + kb + g * 8;
    else                Ab[i] = (const unsigned short*)Ap + (size_t)row * lda + kb + g * 8;
  }
  #pragma unroll
  for (int j = 0; j < 4; ++j)
    Bb[j] = Bp + (size_t)(n0 + j * 16 + lr) * ldb + kb + g * 8;

  #pragma unroll
  for (int t = 0; t < NT; ++t) {
    bf16x8 a[2][2], b[4][2];
    #pragma unroll
    for (int i = 0; i < 2; ++i) {
      #pragma unroll
      for (int kk = 0; kk < 2; ++kk) {
        if constexpr (AF32) {
          float4 f0 = *(const float4*)(Af[i] + t * 64 + kk * 32);
          float4 f1 = *(const float4*)(Af[i] + t * 64 + kk * 32 + 4);
          uint4 pk = { pack2(f0.x, f0.y), pack2(f0.z, f0.w),
                       pack2(f1.x, f1.y), pack2(f1.z, f1.w) };
          a[i][kk] = __builtin_bit_cast(bf16x8, pk);
        } else {
          a[i][kk] = *(const bf16x8*)(Ab[i] + t * 64 + kk * 32);
        }
      }
    }
    #pragma unroll
    for (int j = 0; j < 4; ++j)
      #pragma unroll
      for (int kk = 0; kk < 2; ++kk)
        b[j][kk] = *(const bf16x8*)(Bb[j] + t * 64 + kk * 32);
    #pragma unroll
    for (int kk = 0; kk < 2; ++kk)
      #pragma unroll
      for (int i = 0; i < 2; ++i)
        #pragma unroll
        for (int j = 0; j < 4; ++j)
          acc[i][j] = __builtin_amdgcn_mfma_f32_16x16x32_bf16(a[i][kk], b[j][kk], acc[i][j], 0, 0, 0);
  }

  // epilogue (C/D map: col = lane&15, row = (lane>>4)*4 + r)
  #pragma unroll
  for (int i = 0; i < 2; ++i) {
    int mrow = m0 + i * 16 + g * 4;
    #pragma unroll
    for (int j = 0; j < 4; ++j) {
      int col = n0 + j * 16 + lr;
      if constexpr (EPI == 0) {
        #pragma unroll
        for (int r = 0; r < 4; ++r)
          Cf[(size_t)(mrow + r) * Nld + col] = acc[i][j][r];
      } else if constexpr (EPI == 1) {
        ushort4 st;
        st.x = f2bf(acc[i][j][0]);
        st.y = f2bf(acc[i][j][1]);
        st.z = f2bf(acc[i][j][2]);
        st.w = f2bf(acc[i][j][3]);
        *(ushort4*)&Cb[(size_t)col * Mt + mrow] = st;
      } else {
        #pragma unroll
        for (int r = 0; r < 4; ++r)
          Cb[blockIdx.z * sliceStride + (size_t)(mrow + r) * Nld + col] = f2bf(acc[i][j][r]);
      }
    }
  }
}

// ---------------- Gram + fused symmetric argmin -----------------------------
// A-fragments direct from global (L2-resident x2b); B staged in LDS (dbuf,
// XOR-swizzled, one barrier per K-step). 128x128 block, 2x2 waves (64x64 each).
__launch_bounds__(256)
__global__ void gram_argmin_kernel(const unsigned short* __restrict__ X,
                                   const float* __restrict__ sq,
                                   float* __restrict__ pv, unsigned* __restrict__ pidx) {
  __shared__ alignas(16) unsigned short Bs[2][128 * 64];
  __shared__ float rvv[2][128];
  __shared__ unsigned rvi[2][128];
  __shared__ float cvv[2][128];
  __shared__ unsigned cvi[2][128];

  const int tid = threadIdx.x;
  const int wid = tid >> 6;
  const int lane = tid & 63;
  const int g = lane >> 4;
  const int lr = lane & 15;
  const int wr = wid >> 1;
  const int wc = wid & 1;

  int t = blockIdx.x;            // triangular decode, bj <= bi
  int bi = (int)((sqrtf(8.0f * (float)t + 1.0f) - 1.0f) * 0.5f);
  while ((bi + 1) * (bi + 2) / 2 <= t) ++bi;
  while (bi * (bi + 1) / 2 > t) --bi;
  const int bx = bi;
  const int by = t - bi * (bi + 1) / 2;
  const int m0 = bx * 128;
  const int n0 = by * 128;
  const bool diag = (bx == by);

  f32x4 acc[4][4];
  const f32x4 fzero = {0.f, 0.f, 0.f, 0.f};
  #pragma unroll
  for (int i = 0; i < 4; ++i)
    #pragma unroll
    for (int j = 0; j < 4; ++j) acc[i][j] = fzero;

  auto stageB = [&](int ks, int buf) {
    #pragma unroll
    for (int it = 0; it < 4; ++it) {
      int s = it * 256 + tid;
      int row = s >> 3, cp = s & 7, sc = cp ^ (row & 7);
      __builtin_amdgcn_global_load_lds(
          (const __attribute__((address_space(1))) void*)(X + (size_t)(n0 + row) * 256 + ks * 64 + sc * 8),
          (__attribute__((address_space(3))) void*)&Bs[buf][(it * 256 + wid * 64) * 8], 16, 0, 0);
    }
  };

  stageB(0, 0);
  __syncthreads();

  #pragma unroll
  for (int ks = 0; ks < 4; ++ks) {
    if (ks < 3) stageB(ks + 1, (ks + 1) & 1);
    // A-fragments direct from global (L2)
    bf16x8 a[4][2];
    #pragma unroll
    for (int i = 0; i < 4; ++i)
      #pragma unroll
      for (int kk = 0; kk < 2; ++kk)
        a[i][kk] = *(const bf16x8*)&X[(size_t)(m0 + wr * 64 + i * 16 + lr) * 256 + ks * 64 + kk * 32 + g * 8];
    #pragma unroll
    for (int kk = 0; kk < 2; ++kk) {
      bf16x8 b[4];
      #pragma unroll
      for (int j = 0; j < 4; ++j) {
        int row = wc * 64 + j * 16 + lr;
        int ch = (kk * 4 + g) ^ (row & 7);
        b[j] = *(const bf16x8*)&Bs[ks & 1][row * 64 + ch * 8];
      }
      #pragma unroll
      for (int i = 0; i < 4; ++i)
        #pragma unroll
        for (int j = 0; j < 4; ++j)
          acc[i][j] = __builtin_amdgcn_mfma_f32_16x16x32_bf16(a[i][kk], b[j], acc[i][j], 0, 0, 0);
    }
    __syncthreads();
  }

  // ---- epilogue: per-block partial argmin, no global atomics ----
  int jcol[4];
  float sqj[4], cval[4];
  unsigned cidx[4];
  #pragma unroll
  for (int j = 0; j < 4; ++j) {
    jcol[j] = n0 + wc * 64 + j * 16 + lr;
    sqj[j] = sq[jcol[j]];
    cval[j] = 3.402823466e38f;
    cidx[j] = 0;
  }
  #pragma unroll
  for (int i = 0; i < 4; ++i) {
    #pragma unroll
    for (int r = 0; r < 4; ++r) {
      int irow = m0 + wr * 64 + i * 16 + g * 4 + r;
      float sqi = sq[irow];
      float rval = 3.402823466e38f;
      unsigned ridx = 0;
      #pragma unroll
      for (int j = 0; j < 4; ++j) {
        float gv = acc[i][j][r];
        float rv = fmaf(-2.0f, gv, sqj[j]);
        if (diag && jcol[j] == irow) rv = 3.402823466e38f;
        if (rv < rval) { rval = rv; ridx = (unsigned)jcol[j]; }
        float cv = fmaf(-2.0f, gv, sqi);
        if (cv < cval[j] || (cv == cval[j] && (unsigned)irow < cidx[j])) {
          cval[j] = cv; cidx[j] = (unsigned)irow;
        }
      }
      #pragma unroll
      for (int m = 1; m < 16; m <<= 1) {
        float vo = __shfl_xor(rval, m, 64);
        unsigned io = (unsigned)__shfl_xor((int)ridx, m, 64);
        if (vo < rval || (vo == rval && io < ridx)) { rval = vo; ridx = io; }
      }
      if (lr == 0) {
        int rl = wr * 64 + i * 16 + g * 4 + r;
        rvv[wc][rl] = rval;
        rvi[wc][rl] = ridx;
      }
    }
  }
  if (!diag) {
    #pragma unroll
    for (int j = 0; j < 4; ++j) {
      #pragma unroll
      for (int m = 16; m < 64; m <<= 1) {
        float vo = __shfl_xor(cval[j], m, 64);
        unsigned io = (unsigned)__shfl_xor((int)cidx[j], m, 64);
        if (vo < cval[j] || (vo == cval[j] && io < cidx[j])) { cval[j] = vo; cidx[j] = io; }
      }
      if (g == 0) {
        int cl = wc * 64 + j * 16 + lr;
        cvv[wr][cl] = cval[j];
        cvi[wr][cl] = cidx[j];
      }
    }
  }
  __syncthreads();
  if (tid < 128) {
    float v0 = rvv[0][tid], v1 = rvv[1][tid];
    unsigned i0 = rvi[0][tid], i1 = rvi[1][tid];
    bool take1 = (v1 < v0) || (v1 == v0 && i1 < i0);
    pv[(size_t)by * 8192 + m0 + tid] = take1 ? v1 : v0;
    pidx[(size_t)by * 8192 + m0 + tid] = take1 ? i1 : i0;
  } else if (!diag) {
    int c = tid - 128;
    float v0 = cvv[0][c], v1 = cvv[1][c];
    unsigned i0 = cvi[0][c], i1 = cvi[1][c];
    bool take1 = (v1 < v0) || (v1 == v0 && i1 < i0);
    pv[(size_t)bx * 8192 + n0 + c] = take1 ? v1 : v0;
    pidx[(size_t)bx * 8192 + n0 + c] = take1 ? i1 : i0;
  }
}

// ---------------- launch ----------------

extern "C" void kernel_launch(void* const* d_in, const int* in_sizes, int n_in,
                              void* d_out, int out_size, void* d_ws, size_t ws_size,
                              hipStream_t stream) {
  (void)in_sizes; (void)n_in; (void)out_size; (void)ws_size;
  const float* x   = (const float*)d_in[0];   // [4096][256]
  const float* adj = (const float*)d_in[1];   // [4096][4096]
  const float* W1  = (const float*)d_in[2];   // [256][256]
  const float* W2  = (const float*)d_in[3];   // [256][256]
  float* out = (float*)d_out;                 // [8192][256]

  char* p = (char*)d_ws;
  unsigned short* Tt  = (unsigned short*)p;  p += 4096 * 256 * 2;     // 2MB  (x@W1)^T [256][4096]
  char* R             = p;                   p += 8 * 1024 * 1024;    // 8MB shared-lifetime region
  unsigned short* x2b = (unsigned short*)p;  p += 8192 * 256 * 2;     // 4MB
  float* sqv          = (float*)p;           p += 8192 * 4;
  unsigned* pck       = (unsigned*)p;        p += 8192 * 4;
  unsigned short* W1t = (unsigned short*)p;  p += 256 * 256 * 2;
  unsigned short* W2t = (unsigned short*)p;  p += 256 * 256 * 2;

  // region R overlays (disjoint lifetimes):
  unsigned short* hs = (unsigned short*)R;                  // [4][4096][256] bf16
  float* pv          = (float*)R;                           // [64][8192] f32
  unsigned* pidx     = (unsigned*)(R + 2 * 1024 * 1024);    // [64][8192] u32
  float* support     = (float*)R;                           // [8192][256] f32

  transpose_w_kernel<<<256, 256, 0, stream>>>(W1, W2, W1t, W2t);

  // Tt = (x @ W1)^T : M=4096 N=256 K=256 (EPI1 transposed bf16 out)
  gemm_reg_kernel<4, 1, true><<<dim3(32, 4, 1), 256, 0, stream>>>(
      x, 256, W1t, 256, 256, 4096, 0, nullptr, Tt);

  // h(k-split) = adj @ Tt^T : M=4096 N=256, K split 4 x 1024 (EPI3 bf16 slices)
  gemm_reg_kernel<16, 3, true><<<dim3(32, 4, 4), 256, 0, stream>>>(
      adj, 4096, Tt, 4096, 256, 0, (size_t)4096 * 256, nullptr, hs);

  upsample_kernel<<<2048, 256, 0, stream>>>(hs, x2b, sqv);

  // Gram + fused symmetric argmin partials: triangle of 64x64 chunk grid
  gram_argmin_kernel<<<2080, 256, 0, stream>>>(x2b, sqv, pv, pidx);

  argmin_reduce_kernel<<<32, 256, 0, stream>>>(pv, pidx, pck);

  // support = x2 @ W2 : M=8192 N=256 K=256 (EPI0 fp32 out)
  gemm_reg_kernel<4, 0, false><<<dim3(64, 4, 1), 256, 0, stream>>>(
      x2b, 256, W2t, 256, 256, 0, 0, support, nullptr);

  gather_kernel<<<2048, 256, 0, stream>>>(support, pck, out);
}

// Round 5
// 148.040 us; speedup vs baseline: 1.3607x; 1.3607x over previous
//
#include <hip/hip_runtime.h>
#include <hip/hip_bf16.h>
#include <cstdint>

typedef __attribute__((ext_vector_type(8))) __bf16 bf16x8;
typedef __attribute__((ext_vector_type(4))) float f32x4;

static __device__ __forceinline__ unsigned short f2bf(float f) {
  return __builtin_bit_cast(unsigned short, (__bf16)f);
}
static __device__ __forceinline__ unsigned pack2(float a, float b) {
  return (unsigned)f2bf(a) | ((unsigned)f2bf(b) << 16);
}

// ---------------- small prep kernels ----------------

__global__ void transpose_w_kernel(const float* __restrict__ W1, const float* __restrict__ W2,
                                   unsigned short* __restrict__ W1t, unsigned short* __restrict__ W2t) {
  int i = blockIdx.x * 256 + threadIdx.x;
  int k = i >> 8, n = i & 255;
  W1t[n * 256 + k] = f2bf(W1[k * 256 + n]);
  W2t[n * 256 + k] = f2bf(W2[k * 256 + n]);
}

// x2 = linear2x(sum of 4 bf16 K-split slices of h); vectorized ushort4.
__global__ void upsample_kernel(const unsigned short* __restrict__ hs,  // [4][4096][256]
                                unsigned short* __restrict__ x2b, float* __restrict__ sq) {
  int row = blockIdx.x * 4 + (threadIdx.x >> 6);
  int c = (threadIdx.x & 63) * 4;
  float s = (row + 0.5f) * 0.5f - 0.5f;
  s = fminf(fmaxf(s, 0.0f), 4095.0f);
  float fl = floorf(s);
  int i0 = (int)fl;
  int i1 = min((int)fl + 1, 4095);
  float w = s - fl;
  float v0[4] = {0.f, 0.f, 0.f, 0.f}, v1[4] = {0.f, 0.f, 0.f, 0.f};
  #pragma unroll
  for (int k = 0; k < 4; ++k) {
    ushort4 u0 = *(const ushort4*)&hs[(size_t)k * 4096 * 256 + i0 * 256 + c];
    ushort4 u1 = *(const ushort4*)&hs[(size_t)k * 4096 * 256 + i1 * 256 + c];
    v0[0] += __builtin_bit_cast(float, (unsigned)u0.x << 16);
    v0[1] += __builtin_bit_cast(float, (unsigned)u0.y << 16);
    v0[2] += __builtin_bit_cast(float, (unsigned)u0.z << 16);
    v0[3] += __builtin_bit_cast(float, (unsigned)u0.w << 16);
    v1[0] += __builtin_bit_cast(float, (unsigned)u1.x << 16);
    v1[1] += __builtin_bit_cast(float, (unsigned)u1.y << 16);
    v1[2] += __builtin_bit_cast(float, (unsigned)u1.z << 16);
    v1[3] += __builtin_bit_cast(float, (unsigned)u1.w << 16);
  }
  float p = 0.f;
  ushort4 st;
  unsigned short* sp = (unsigned short*)&st;
  #pragma unroll
  for (int e = 0; e < 4; ++e) {
    float v = v0[e] * (1.0f - w) + v1[e] * w;
    sp[e] = f2bf(v);
    p += v * v;
  }
  *(ushort4*)&x2b[(size_t)row * 256 + c] = st;
  #pragma unroll
  for (int m = 32; m > 0; m >>= 1) p += __shfl_down(p, m, 64);
  if ((threadIdx.x & 63) == 0) sq[row] = p;
}

// final per-row lex-min over the 32 partial slots
__global__ void argmin_reduce_kernel(const float* __restrict__ pv,
                                     const unsigned* __restrict__ pidx,
                                     unsigned* __restrict__ pck) {
  int row = blockIdx.x * 256 + threadIdx.x;
  float bv = 3.402823466e38f;
  unsigned bidx = 0;
  for (int c = 0; c < 32; ++c) {
    float v = pv[(size_t)c * 8192 + row];
    unsigned id = pidx[(size_t)c * 8192 + row];
    if (v < bv || (v == bv && id < bidx)) { bv = v; bidx = id; }
  }
  pck[row] = bidx;
}

__global__ void gather_kernel(const float* __restrict__ support,
                              const unsigned* __restrict__ pck,
                              float* __restrict__ out) {
  int gid = blockIdx.x * 256 + threadIdx.x;
  int row = gid >> 6;
  int c4 = (gid & 63) * 4;
  unsigned idx = pck[row];
  *(float4*)&out[(size_t)row * 256 + c4] = *(const float4*)&support[(size_t)idx * 256 + c4];
}

// ---------------- Gram + fused symmetric argmin, 256^2 tile, 8 waves ---------
// X: [8192][256] bf16. Triangular grid over 32x32 chunk pairs (bi >= bj).
// 8 waves as 2(M) x 4(N); wave tile 128x64; BK=64; dbuf LDS 128KB.
__launch_bounds__(512)
__global__ void gram_argmin_kernel(const unsigned short* __restrict__ X,
                                   const float* __restrict__ sq,
                                   float* __restrict__ pv, unsigned* __restrict__ pidx) {
  __shared__ alignas(16) unsigned char smem[131072];   // buf b: A @ b*65536, B @ +32768

  const int tid = threadIdx.x;
  const int wid = tid >> 6;
  const int lane = tid & 63;
  const int g = lane >> 4;
  const int lr = lane & 15;
  const int wr = wid >> 2;     // 0..1
  const int wc = wid & 3;      // 0..3

  int t = blockIdx.x;          // triangular decode, bj <= bi
  int bi = (int)((sqrtf(8.0f * (float)t + 1.0f) - 1.0f) * 0.5f);
  while ((bi + 1) * (bi + 2) / 2 <= t) ++bi;
  while (bi * (bi + 1) / 2 > t) --bi;
  const int bx = bi;
  const int by = t - bi * (bi + 1) / 2;
  const int m0 = bx * 256;
  const int n0 = by * 256;
  const bool diag = (bx == by);

  f32x4 acc[8][4];
  const f32x4 fzero = {0.f, 0.f, 0.f, 0.f};
  #pragma unroll
  for (int i = 0; i < 8; ++i)
    #pragma unroll
    for (int j = 0; j < 4; ++j) acc[i][j] = fzero;

  auto stage = [&](int ks, int buf) {
    unsigned char* Ab = smem + buf * 65536;
    unsigned char* Bb = smem + buf * 65536 + 32768;
    #pragma unroll
    for (int it = 0; it < 4; ++it) {
      int s = it * 512 + tid;
      int row = s >> 3, cp = s & 7, sc = cp ^ (row & 7);
      __builtin_amdgcn_global_load_lds(
          (const __attribute__((address_space(1))) void*)(X + (size_t)(m0 + row) * 256 + ks * 64 + sc * 8),
          (__attribute__((address_space(3))) void*)(Ab + (size_t)(it * 512 + wid * 64) * 16), 16, 0, 0);
    }
    #pragma unroll
    for (int it = 0; it < 4; ++it) {
      int s = it * 512 + tid;
      int row = s >> 3, cp = s & 7, sc = cp ^ (row & 7);
      __builtin_amdgcn_global_load_lds(
          (const __attribute__((address_space(1))) void*)(X + (size_t)(n0 + row) * 256 + ks * 64 + sc * 8),
          (__attribute__((address_space(3))) void*)(Bb + (size_t)(it * 512 + wid * 64) * 16), 16, 0, 0);
    }
  };

  stage(0, 0);
  __syncthreads();

  #pragma unroll
  for (int ks = 0; ks < 4; ++ks) {
    const int buf = ks & 1;
    if (ks < 3) stage(ks + 1, buf ^ 1);
    const unsigned short* As = (const unsigned short*)(smem + buf * 65536);
    const unsigned short* Bs = (const unsigned short*)(smem + buf * 65536 + 32768);
    #pragma unroll
    for (int kk = 0; kk < 2; ++kk) {
      bf16x8 b[4];
      #pragma unroll
      for (int j = 0; j < 4; ++j) {
        int row = wc * 64 + j * 16 + lr;
        int ch = (kk * 4 + g) ^ (row & 7);
        b[j] = *(const bf16x8*)&Bs[row * 64 + ch * 8];
      }
      #pragma unroll
      for (int i = 0; i < 8; ++i) {
        int row = wr * 128 + i * 16 + lr;
        int ch = (kk * 4 + g) ^ (row & 7);
        bf16x8 a = *(const bf16x8*)&As[row * 64 + ch * 8];
        #pragma unroll
        for (int j = 0; j < 4; ++j)
          acc[i][j] = __builtin_amdgcn_mfma_f32_16x16x32_bf16(a, b[j], acc[i][j], 0, 0, 0);
      }
    }
    __syncthreads();   // drains vmcnt of the just-issued next stage too
  }

  // ---- epilogue: partial argmin into LDS (reuse dead A-buffer), no atomics --
  float* rvv    = (float*)smem;                 // [4][256]
  unsigned* rvi = (unsigned*)(smem + 4096);     // [4][256]
  float* cvv    = (float*)(smem + 8192);        // [2][256]
  unsigned* cvi = (unsigned*)(smem + 10240);    // [2][256]

  int jcol[4];
  float sqj[4], cval[4];
  unsigned cidx[4];
  #pragma unroll
  for (int j = 0; j < 4; ++j) {
    jcol[j] = n0 + wc * 64 + j * 16 + lr;
    sqj[j] = sq[jcol[j]];
    cval[j] = 3.402823466e38f;
    cidx[j] = 0;
  }
  #pragma unroll
  for (int i = 0; i < 8; ++i) {
    #pragma unroll
    for (int r = 0; r < 4; ++r) {
      int lrow = wr * 128 + i * 16 + g * 4 + r;
      int irow = m0 + lrow;
      float sqi = sq[irow];
      float rval = 3.402823466e38f;
      unsigned ridx = 0;
      #pragma unroll
      for (int j = 0; j < 4; ++j) {
        float gv = acc[i][j][r];
        float rv = fmaf(-2.0f, gv, sqj[j]);     // value = sq[cand] - 2G (query-row const dropped)
        if (diag && jcol[j] == irow) rv = 3.402823466e38f;
        if (rv < rval) { rval = rv; ridx = (unsigned)jcol[j]; }
        float cv = fmaf(-2.0f, gv, sqi);
        if (cv < cval[j] || (cv == cval[j] && (unsigned)irow < cidx[j])) {
          cval[j] = cv; cidx[j] = (unsigned)irow;
        }
      }
      #pragma unroll
      for (int m = 1; m < 16; m <<= 1) {
        float vo = __shfl_xor(rval, m, 64);
        unsigned io = (unsigned)__shfl_xor((int)ridx, m, 64);
        if (vo < rval || (vo == rval && io < ridx)) { rval = vo; ridx = io; }
      }
      if (lr == 0) {
        rvv[wc * 256 + lrow] = rval;
        rvi[wc * 256 + lrow] = ridx;
      }
    }
  }
  if (!diag) {
    #pragma unroll
    for (int j = 0; j < 4; ++j) {
      #pragma unroll
      for (int m = 16; m < 64; m <<= 1) {
        float vo = __shfl_xor(cval[j], m, 64);
        unsigned io = (unsigned)__shfl_xor((int)cidx[j], m, 64);
        if (vo < cval[j] || (vo == cval[j] && io < cidx[j])) { cval[j] = vo; cidx[j] = io; }
      }
      if (g == 0) {
        int lcol = wc * 64 + j * 16 + lr;
        cvv[wr * 256 + lcol] = cval[j];
        cvi[wr * 256 + lcol] = cidx[j];
      }
    }
  }
  __syncthreads();
  if (tid < 256) {
    float bv = rvv[tid];
    unsigned bidx = rvi[tid];
    #pragma unroll
    for (int w = 1; w < 4; ++w) {
      float v = rvv[w * 256 + tid];
      unsigned id = rvi[w * 256 + tid];
      if (v < bv || (v == bv && id < bidx)) { bv = v; bidx = id; }
    }
    pv[(size_t)by * 8192 + m0 + tid] = bv;
    pidx[(size_t)by * 8192 + m0 + tid] = bidx;
  } else if (!diag) {
    int c = tid - 256;
    float v0 = cvv[c], v1 = cvv[256 + c];
    unsigned i0 = cvi[c], i1 = cvi[256 + c];
    bool take1 = (v1 < v0) || (v1 == v0 && i1 < i0);
    pv[(size_t)bx * 8192 + n0 + c] = take1 ? v1 : v0;
    pidx[(size_t)bx * 8192 + n0 + c] = take1 ? i1 : i0;
  }
}

// ---------------- LDS-staged GEMM-NT (C = A * B^T), 2-phase dbuf ------------
// A: [M][K] (fp32 if AF32 else bf16), lda=K. B: [N][K] bf16, ldb=K.
// EPI 0: Cf[m][n] fp32.  EPI 1: Ct[n][m] bf16 transposed.
// EPI 3: Cb[m][n] bf16, K-split: kbase = blockIdx.y*K, out += blockIdx.y*M*N.
template <int BM, int BN, int WAVES_M, int EPI, bool AF32>
__launch_bounds__(256)
__global__ void gemm_nt_kernel(const void* __restrict__ Ap, int lda,
                               const unsigned short* __restrict__ Bp, int ldb,
                               int M, int N, int K,
                               float* __restrict__ Cf,
                               unsigned short* __restrict__ Cb) {
  constexpr int BK = 64;
  constexpr int WAVES_N = 4 / WAVES_M;
  constexpr int WM = BM / WAVES_M;
  constexpr int WN = BN / WAVES_N;
  constexpr int FM = WM / 16;
  constexpr int FN = WN / 16;
  constexpr int ASLOT = BM * 8;
  constexpr int AITER = (ASLOT + 255) / 256;
  constexpr int BITER = (BN * 8) / 256;

  __shared__ alignas(16) unsigned short As0[BM * BK], As1[BM * BK];
  __shared__ alignas(16) unsigned short Bs0[BN * BK], Bs1[BN * BK];

  const int tid = threadIdx.x;
  const int wid = tid >> 6;
  const int lane = tid & 63;
  const int g = lane >> 4;
  const int lr = lane & 15;
  const int wr = wid / WAVES_N;
  const int wc = wid % WAVES_N;
  const int m0 = blockIdx.x * BM;
  const int n0 = (EPI == 3) ? 0 : blockIdx.y * BN;
  const int kbase = (EPI == 3) ? blockIdx.y * K : 0;
  if constexpr (EPI == 3) Cb += (size_t)blockIdx.y * (size_t)M * (size_t)N;

  f32x4 acc[FM][FN];
  const f32x4 fzero = {0.f, 0.f, 0.f, 0.f};
  #pragma unroll
  for (int i = 0; i < FM; ++i)
    #pragma unroll
    for (int j = 0; j < FN; ++j) acc[i][j] = fzero;

  float4 ar[AITER][2];

  auto issueA = [&](int k0, unsigned short* Asd) {
    if constexpr (AF32) {
      const float* A = (const float*)Ap;
      #pragma unroll
      for (int it = 0; it < AITER; ++it) {
        int s = it * 256 + tid;
        if (ASLOT % 256 == 0 || s < ASLOT) {
          int row = s >> 3, cp = s & 7, sc = cp ^ (row & 7);
          const float* src = A + (size_t)(m0 + row) * (size_t)lda + kbase + k0 + sc * 8;
          ar[it][0] = *(const float4*)src;
          ar[it][1] = *(const float4*)(src + 4);
        }
      }
    } else {
      const unsigned short* A = (const unsigned short*)Ap;
      #pragma unroll
      for (int it = 0; it < AITER; ++it) {
        int s = it * 256 + tid;
        int row = s >> 3, cp = s & 7, sc = cp ^ (row & 7);
        const unsigned short* src = A + (size_t)(m0 + row) * (size_t)lda + kbase + k0 + sc * 8;
        __builtin_amdgcn_global_load_lds(
            (const __attribute__((address_space(1))) void*)src,
            (__attribute__((address_space(3))) void*)(Asd + (size_t)(it * 256 + wid * 64) * 8),
            16, 0, 0);
      }
    }
  };
  auto writeA = [&](unsigned short* Asd) {
    if constexpr (AF32) {
      #pragma unroll
      for (int it = 0; it < AITER; ++it) {
        int s = it * 256 + tid;
        if (ASLOT % 256 == 0 || s < ASLOT) {
          int row = s >> 3, cp = s & 7;
          uint4 pk = { pack2(ar[it][0].x, ar[it][0].y), pack2(ar[it][0].z, ar[it][0].w),
                       pack2(ar[it][1].x, ar[it][1].y), pack2(ar[it][1].z, ar[it][1].w) };
          *(uint4*)&Asd[row * BK + cp * 8] = pk;
        }
      }
    }
  };
  auto issueB = [&](int k0, unsigned short* Bsd) {
    #pragma unroll
    for (int it = 0; it < BITER; ++it) {
      int s = it * 256 + tid;
      int row = s >> 3, cp = s & 7, sc = cp ^ (row & 7);
      const unsigned short* src = Bp + (size_t)(n0 + row) * (size_t)ldb + kbase + k0 + sc * 8;
      __builtin_amdgcn_global_load_lds(
          (const __attribute__((address_space(1))) void*)src,
          (__attribute__((address_space(3))) void*)(Bsd + (size_t)(it * 256 + wid * 64) * 8),
          16, 0, 0);
    }
  };
  auto compute = [&](const unsigned short* Asd, const unsigned short* Bsd) {
    #pragma unroll
    for (int kk = 0; kk < 2; ++kk) {
      bf16x8 a[FM], b[FN];
      #pragma unroll
      for (int i = 0; i < FM; ++i) {
        int row = wr * WM + i * 16 + lr;
        int ch = (kk * 4 + g) ^ (row & 7);
        a[i] = *(const bf16x8*)&Asd[row * BK + ch * 8];
      }
      #pragma unroll
      for (int j = 0; j < FN; ++j) {
        int row = wc * WN + j * 16 + lr;
        int ch = (kk * 4 + g) ^ (row & 7);
        b[j] = *(const bf16x8*)&Bsd[row * BK + ch * 8];
      }
      #pragma unroll
      for (int i = 0; i < FM; ++i)
        #pragma unroll
        for (int j = 0; j < FN; ++j)
          acc[i][j] = __builtin_amdgcn_mfma_f32_16x16x32_bf16(a[i], b[j], acc[i][j], 0, 0, 0);
    }
  };

  issueA(0, As0);
  issueB(0, Bs0);
  writeA(As0);
  __syncthreads();

  const int nt = K / BK;
  for (int t = 0; t < nt; t += 2) {
    if (t + 1 < nt) { issueA((t + 1) * BK, As1); issueB((t + 1) * BK, Bs1); }
    compute(As0, Bs0);
    if (t + 1 < nt) writeA(As1);
    __syncthreads();
    if (t + 2 < nt) { issueA((t + 2) * BK, As0); issueB((t + 2) * BK, Bs0); }
    compute(As1, Bs1);
    if (t + 2 < nt) writeA(As0);
    __syncthreads();
  }

  const int rowb = wr * WM;
  const int colb = wc * WN;
  if constexpr (EPI == 0) {
    #pragma unroll
    for (int i = 0; i < FM; ++i) {
      int mrow = m0 + rowb + i * 16 + g * 4;
      #pragma unroll
      for (int j = 0; j < FN; ++j) {
        int col = n0 + colb + j * 16 + lr;
        #pragma unroll
        for (int r = 0; r < 4; ++r)
          Cf[(size_t)(mrow + r) * N + col] = acc[i][j][r];
      }
    }
  } else if constexpr (EPI == 1) {
    #pragma unroll
    for (int i = 0; i < FM; ++i) {
      int mrow = m0 + rowb + i * 16 + g * 4;
      #pragma unroll
      for (int j = 0; j < FN; ++j) {
        int col = n0 + colb + j * 16 + lr;
        ushort4 st;
        st.x = f2bf(acc[i][j][0]);
        st.y = f2bf(acc[i][j][1]);
        st.z = f2bf(acc[i][j][2]);
        st.w = f2bf(acc[i][j][3]);
        *(ushort4*)&Cb[(size_t)col * M + mrow] = st;
      }
    }
  } else {
    #pragma unroll
    for (int i = 0; i < FM; ++i) {
      int mrow = m0 + rowb + i * 16 + g * 4;
      #pragma unroll
      for (int j = 0; j < FN; ++j) {
        int col = n0 + colb + j * 16 + lr;
        #pragma unroll
        for (int r = 0; r < 4; ++r)
          Cb[(size_t)(mrow + r) * N + col] = f2bf(acc[i][j][r]);
      }
    }
  }
}

// ---------------- launch ----------------

extern "C" void kernel_launch(void* const* d_in, const int* in_sizes, int n_in,
                              void* d_out, int out_size, void* d_ws, size_t ws_size,
                              hipStream_t stream) {
  (void)in_sizes; (void)n_in; (void)out_size; (void)ws_size;
  const float* x   = (const float*)d_in[0];   // [4096][256]
  const float* adj = (const float*)d_in[1];   // [4096][4096]
  const float* W1  = (const float*)d_in[2];   // [256][256]
  const float* W2  = (const float*)d_in[3];   // [256][256]
  float* out = (float*)d_out;                 // [8192][256]

  char* p = (char*)d_ws;
  unsigned short* Tt  = (unsigned short*)p;  p += 4096 * 256 * 2;     // 2MB  (x@W1)^T [256][4096]
  char* R             = p;                   p += 8 * 1024 * 1024;    // 8MB shared-lifetime region
  unsigned short* x2b = (unsigned short*)p;  p += 8192 * 256 * 2;     // 4MB
  float* sqv          = (float*)p;           p += 8192 * 4;
  unsigned* pck       = (unsigned*)p;        p += 8192 * 4;
  unsigned short* W1t = (unsigned short*)p;  p += 256 * 256 * 2;
  unsigned short* W2t = (unsigned short*)p;  p += 256 * 256 * 2;

  // region R overlays (disjoint lifetimes):
  unsigned short* hs = (unsigned short*)R;                  // [4][4096][256] bf16
  float* pv          = (float*)R;                           // [32][8192] f32 (1MB)
  unsigned* pidx     = (unsigned*)(R + 1 * 1024 * 1024);    // [32][8192] u32 (1MB)
  float* support     = (float*)R;                           // [8192][256] f32 (8MB)

  transpose_w_kernel<<<256, 256, 0, stream>>>(W1, W2, W1t, W2t);

  // Tt = (x @ W1)^T : M=4096 N=256 K=256 (EPI1 transposed bf16 out)
  gemm_nt_kernel<64, 64, 4, 1, true><<<dim3(64, 4), 256, 0, stream>>>(
      x, 256, W1t, 256, 4096, 256, 256, nullptr, Tt);

  // h(k-split) = adj @ Tt^T : BM=64 BN=256, K split 4x1024 -> 256 blocks
  gemm_nt_kernel<64, 256, 2, 3, true><<<dim3(64, 4), 256, 0, stream>>>(
      adj, 4096, Tt, 4096, 4096, 256, 1024, nullptr, hs);

  upsample_kernel<<<2048, 256, 0, stream>>>(hs, x2b, sqv);

  // Gram + fused symmetric argmin partials: triangle of 32x32 chunk grid
  gram_argmin_kernel<<<528, 512, 0, stream>>>(x2b, sqv, pv, pidx);

  argmin_reduce_kernel<<<32, 256, 0, stream>>>(pv, pidx, pck);

  // support = x2 @ W2 : M=8192 N=256 K=256 (EPI0 fp32 out)
  gemm_nt_kernel<64, 64, 4, 0, false><<<dim3(128, 4), 256, 0, stream>>>(
      x2b, 256, W2t, 256, 8192, 256, 256, support, nullptr);

  gather_kernel<<<2048, 256, 0, stream>>>(support, pck, out);
}